// Round 14
// baseline (617.359 us; speedup 1.0000x reference)
//
#include <hip/hip_runtime.h>
#include <hip/hip_bf16.h>
#include <stdint.h>

#define DIMD 1024
#define NB 4
#define NT 2048
#define NH 16
#define BT (NB*NT)      /* 8192 */
#define NQKV (3*DIMD)   /* 3072 */

typedef __attribute__((ext_vector_type(8))) __bf16 bf16x8;
typedef __attribute__((ext_vector_type(4))) __bf16 bf16x4;
typedef __attribute__((ext_vector_type(4))) float f32x4;
typedef __attribute__((ext_vector_type(16))) float f32x16;

#define MFMA16(a,b,c) __builtin_amdgcn_mfma_f32_16x16x32_bf16((a),(b),(c),0,0,0)
#define MFMA32(a,b,c) __builtin_amdgcn_mfma_f32_32x32x16_bf16((a),(b),(c),0,0,0)

// (1/sqrt(1024)) * log2(e) — folded into Q at projection time
#define QSCALE 0.0450842200277801f

__device__ __forceinline__ void gld16(const void* g, void* l) {
  __builtin_amdgcn_global_load_lds((const __attribute__((address_space(1))) void*)g,
                                   (__attribute__((address_space(3))) void*)l,
                                   16, 0, 0);
}

__device__ __forceinline__ unsigned pkbf(float a, float b) {
  unsigned short ua = __builtin_bit_cast(unsigned short, (__bf16)a);
  unsigned short ub = __builtin_bit_cast(unsigned short, (__bf16)b);
  return (unsigned)ua | ((unsigned)ub << 16);
}

// ---------------- fused prep: X f32->bf16  +  transpose-convert of both weights ----------
__global__ __launch_bounds__(256) void k_prep(const float* __restrict__ X,
                                              const float* __restrict__ Wqkv,
                                              const float* __restrict__ Wout,
                                              __bf16* __restrict__ Xb,
                                              __bf16* __restrict__ Wqt,
                                              __bf16* __restrict__ Wot) {
  __shared__ __bf16 t[64][72];
  const int bid = blockIdx.x, tid = threadIdx.x;
  if (bid < 1024) {
    const float* in; __bf16* out; int K, N, n0, k0;
    if (bid < 768) { in = Wqkv; out = Wqt; K = 1024; N = 3072; n0 = (bid % 48) * 64; k0 = (bid / 48) * 64; }
    else { int id = bid - 768; in = Wout; out = Wot; K = 1024; N = 1024; n0 = (id % 16) * 64; k0 = (id / 16) * 64; }
    int r = tid >> 2, c0 = (tid & 3) * 16;
    const float4* src = (const float4*)(in + (size_t)(k0 + r) * N + n0 + c0);
#pragma unroll
    for (int i = 0; i < 4; ++i) {
      float4 v = src[i];
      t[r][c0 + i*4 + 0] = (__bf16)v.x;
      t[r][c0 + i*4 + 1] = (__bf16)v.y;
      t[r][c0 + i*4 + 2] = (__bf16)v.z;
      t[r][c0 + i*4 + 3] = (__bf16)v.w;
    }
    __syncthreads();
    bf16x8 o0, o1;
#pragma unroll
    for (int i = 0; i < 8; ++i) o0[i] = t[c0 + i][r];
#pragma unroll
    for (int i = 0; i < 8; ++i) o1[i] = t[c0 + 8 + i][r];
    __bf16* dst = out + (size_t)(n0 + r) * K + k0 + c0;
    *(bf16x8*)dst = o0;
    *(bf16x8*)(dst + 8) = o1;
  } else {
    const int n4 = (BT * DIMD) / 4;
    int i = (bid - 1024) * 256 + tid;
    const int st = 2048 * 256;
    for (; i < n4; i += st) {
      float4 v = ((const float4*)X)[i];
      bf16x4 o;
      o[0] = (__bf16)v.x; o[1] = (__bf16)v.y; o[2] = (__bf16)v.z; o[3] = (__bf16)v.w;
      ((bf16x4*)Xb)[i] = o;
    }
  }
}

// ---------------- GEMM 128x128, ring-3 LDS, counted vmcnt, 3 blocks/CU ----------------
template<int MODE>
__global__ __launch_bounds__(256, 3) void k_gemm128(const __bf16* __restrict__ A,
                                                    const __bf16* __restrict__ Bt,
                                                    int nbx,
                                                    __bf16* __restrict__ oQK,
                                                    __bf16* __restrict__ oVt,
                                                    float* __restrict__ oF,
                                                    const float* __restrict__ bias) {
  constexpr int KK = 1024, KT = 32;
  __shared__ alignas(16) char L[3 * 16384];
  const int tid = threadIdx.x;
  const int lane = tid & 63, wid = tid >> 6;
  const int lr = lane & 15, lo = lane >> 4;
  const int wm = wid >> 1, wn = wid & 1;
  const int cpx = gridDim.x >> 3;   // grid % 8 == 0 for both launches
  const int swz = (blockIdx.x & 7) * cpx + (blockIdx.x >> 3);
  const int bx = swz % nbx, by = swz / nbx;
  const int m0 = by * 128, n0 = bx * 128;

  const char* gp[4];
  int loff[4];
#pragma unroll
  for (int j = 0; j < 4; ++j) {
    int c = j * 256 + tid;
    int isB = (c >= 512);
    int lc = c & 511;
    int row = lc >> 2, kof = (lc & 3) * 8;
    const __bf16* base = isB ? (Bt + (size_t)(n0 + row) * KK + kof)
                             : (A + (size_t)(m0 + row) * KK + kof);
    gp[j] = (const char*)base;
    loff[j] = c * 16;
  }
  auto STAGE = [&](int s) {
    char* bas = L + s * 16384;
    gld16(gp[0], bas + loff[0]); gp[0] += 64;
    gld16(gp[1], bas + loff[1]); gp[1] += 64;
    gld16(gp[2], bas + loff[2]); gp[2] += 64;
    gld16(gp[3], bas + loff[3]); gp[3] += 64;
  };

  f32x4 acc[4][4] = {};
  STAGE(0); STAGE(1);
  int xs = 2;

  for (int t = 0; t < KT; ++t) {
    if (t == KT - 1) asm volatile("s_waitcnt vmcnt(0)" ::: "memory");
    else             asm volatile("s_waitcnt vmcnt(4)" ::: "memory");
    asm volatile("s_barrier" ::: "memory");
    if (t <= KT - 3) { STAGE(xs); xs = (xs == 2) ? 0 : xs + 1; }
    const __bf16* fa = (const __bf16*)(L + (t % 3) * 16384) + (wm * 64 + lr) * 32 + lo * 8;
    const __bf16* fb = (const __bf16*)(L + (t % 3) * 16384 + 8192) + (wn * 64 + lr) * 32 + lo * 8;
    bf16x8 Af[4], Bf[4];
#pragma unroll
    for (int i = 0; i < 4; ++i) Af[i] = *(const bf16x8*)(fa + i * 512);
#pragma unroll
    for (int j = 0; j < 4; ++j) Bf[j] = *(const bf16x8*)(fb + j * 512);
    __builtin_amdgcn_s_setprio(1);
#pragma unroll
    for (int i = 0; i < 4; ++i)
#pragma unroll
      for (int j = 0; j < 4; ++j)
        acc[i][j] = MFMA16(Af[i], Bf[j], acc[i][j]);
    __builtin_amdgcn_s_setprio(0);
  }

  const int mb = m0 + wm * 64 + lo * 4;
  if (MODE == 0) {
    if (n0 < 1024) {        // Q: fold softmax scale in f32 (no extra rounding)
#pragma unroll
      for (int i = 0; i < 4; ++i)
#pragma unroll
        for (int j = 0; j < 4; ++j) {
          int col = n0 + wn * 64 + j * 16 + lr;
          int row = mb + i * 16;
#pragma unroll
          for (int r = 0; r < 4; ++r)
            oQK[(size_t)(row + r) * 2048 + col] = (__bf16)(acc[i][j][r] * QSCALE);
        }
    } else if (n0 < 2048) { // K
#pragma unroll
      for (int i = 0; i < 4; ++i)
#pragma unroll
        for (int j = 0; j < 4; ++j) {
          int col = n0 + wn * 64 + j * 16 + lr;
          int row = mb + i * 16;
#pragma unroll
          for (int r = 0; r < 4; ++r)
            oQK[(size_t)(row + r) * 2048 + col] = (__bf16)acc[i][j][r];
        }
    } else {                // V: write transposed Vt[b][d][t]
#pragma unroll
      for (int i = 0; i < 4; ++i)
#pragma unroll
        for (int j = 0; j < 4; ++j) {
          int dd = n0 - 2048 + wn * 64 + j * 16 + lr;
          int row = mb + i * 16;
          int bb = row >> 11, tt = row & 2047;
          bf16x4 pk;
#pragma unroll
          for (int r = 0; r < 4; ++r) pk[r] = (__bf16)acc[i][j][r];
          *(bf16x4*)(oVt + ((size_t)(bb << 10) + dd) * 2048 + tt) = pk;
        }
    }
  } else {
#pragma unroll
    for (int i = 0; i < 4; ++i)
#pragma unroll
      for (int j = 0; j < 4; ++j) {
        int col = n0 + wn * 64 + j * 16 + lr;
        float bv = bias[col];
        int row = mb + i * 16;
#pragma unroll
        for (int r = 0; r < 4; ++r)
          oF[(size_t)(row + r) * 1024 + col] = acc[i][j][r] + bv;
      }
  }
}

// ---------------- flash attention: KV-split x2, 8 waves, 4 waves/SIMD --------------------
// 512 thr: waves 0-3 do KV[0:1024), waves 4-7 do KV[1024:2048) for the SAME 256 q-rows.
// Fixed-shift softmax (no max) => partials combine by ADDITION: O = sum(O_g)/sum(ln_g).
// Per-group ring-2 LDS (2 x 18432 B); stage 1 ahead; vmcnt(0) at tile top (load had a
// full tile of compute to land; 4 waves/SIMD cover residual stalls).
// Combine: group 1 writes O (quad-interleaved, conflict-free) + ln to LDS; group 0 adds.
__global__ __launch_bounds__(512, 4) void k_attn(const __bf16* __restrict__ QK,
                                                 const __bf16* __restrict__ Vt,
                                                 __bf16* __restrict__ AO) {
  __shared__ alignas(16) char Lsm[73728];   // 2 groups x ring-2 x 18432; combine overlays
  const int tid = threadIdx.x, w = tid >> 6, lane = tid & 63;
  const int wg = w & 3, g = w >> 2;
  const int tid_g = tid & 255;
  const int l31 = lane & 31, hi = lane >> 5;
  const int P = blockIdx.x;
  const int low3 = P & 7, gg = P >> 3;
  const int qc = gg & 7;
  const int bh = ((gg >> 3) << 3) + low3;
  const int h = bh & 15, b = bh >> 4;
  const int q0 = qc * 256 + wg * 64;

  bf16x8 qfA[4], qfB[4];
  {
    const __bf16* Qb = QK + (size_t)(b * 2048 + q0 + l31) * 2048 + h * 64 + hi * 8;
#pragma unroll
    for (int dc = 0; dc < 4; ++dc) qfA[dc] = *(const bf16x8*)(Qb + dc * 16);
    Qb += (size_t)32 * 2048;
#pragma unroll
    for (int dc = 0; dc < 4; ++dc) qfB[dc] = *(const bf16x8*)(Qb + dc * 16);
  }
  // group-local K/V bases (group g covers kv in [g*1024, g*1024+1024))
  const __bf16* Kg = QK + (size_t)(b * 2048 + g * 1024) * 2048 + 1024 + h * 64;
  const __bf16* Vg = Vt + (size_t)(b * 1024 + h * 64) * 2048 + g * 1024;

  // staging: 1152 chunks/tile per group over 256 threads (tid_g); lc -> row=lc/9,col=lc%9
  const bool nch5 = (tid_g < 128);
  const char* gp[5];
  int loff[5], advB[5];
#pragma unroll
  for (int j = 0; j < 5; ++j) {
    int c = (j < 4) ? (j * 256 + tid_g) : (1024 + tid_g);
    if (c > 1151) c = 1151;
    int isV = (c >= 576);
    int lc = isV ? c - 576 : c;
    int row = lc / 9, col = lc - row * 9; if (col == 8) col = 0;
    const __bf16* gsrc = isV ? (Vg + (size_t)row * 2048 + col * 8)
                             : (Kg + (size_t)row * 2048 + col * 8);
    gp[j] = (const char*)gsrc;
    loff[j] = c * 16;
    advB[j] = isV ? 128 : 262144;
  }

  char* ring = Lsm + g * 36864;

  f32x16 oA0 = {0,0,0,0,0,0,0,0,0,0,0,0,0,0,0,0};
  f32x16 oA1 = {0,0,0,0,0,0,0,0,0,0,0,0,0,0,0,0};
  f32x16 oB0 = {0,0,0,0,0,0,0,0,0,0,0,0,0,0,0,0};
  f32x16 oB1 = {0,0,0,0,0,0,0,0,0,0,0,0,0,0,0,0};
  float lnA = 0.f, lnB = 0.f;

  auto STAGE = [&](int s) {
    char* bas = ring + s * 18432;
    gld16(gp[0], bas + loff[0]); gp[0] += advB[0];
    gld16(gp[1], bas + loff[1]); gp[1] += advB[1];
    gld16(gp[2], bas + loff[2]); gp[2] += advB[2];
    gld16(gp[3], bas + loff[3]); gp[3] += advB[3];
    if (nch5) { gld16(gp[4], bas + loff[4]); gp[4] += advB[4]; }
  };

  auto SMPACK = [&](const f32x16& s0, const f32x16& s1, unsigned pw[4][4], float& ln) {
    float p0a[16], p1a[16];
#pragma unroll
    for (int r = 0; r < 16; ++r) {
      p0a[r] = __builtin_amdgcn_exp2f(s0[r]);
      p1a[r] = __builtin_amdgcn_exp2f(s1[r]);
    }
    float sA = 0.f, sB = 0.f, sC = 0.f, sD = 0.f;
#pragma unroll
    for (int r = 0; r < 4; ++r) {
      sA += p0a[r];      sB += p0a[4 + r];
      sC += p0a[8 + r];  sD += p0a[12 + r];
      sA += p1a[r];      sB += p1a[4 + r];
      sC += p1a[8 + r];  sD += p1a[12 + r];
    }
    ln += (sA + sB) + (sC + sD);
#pragma unroll
    for (int c = 0; c < 4; ++c) {
      const float* pp = (c < 2) ? p0a : p1a;
      const int rb = (c & 1) * 8;
      unsigned A01 = pkbf(pp[rb + 0], pp[rb + 1]);
      unsigned A23 = pkbf(pp[rb + 2], pp[rb + 3]);
      unsigned A45 = pkbf(pp[rb + 4], pp[rb + 5]);
      unsigned A67 = pkbf(pp[rb + 6], pp[rb + 7]);
      asm("v_permlane32_swap_b32 %0, %1" : "+v"(A01), "+v"(A45));
      asm("v_permlane32_swap_b32 %0, %1" : "+v"(A23), "+v"(A67));
      pw[c][0] = A01; pw[c][1] = A23; pw[c][2] = A45; pw[c][3] = A67;
    }
  };

  STAGE(0);

  for (int t = 0; t < 16; ++t) {
    asm volatile("s_waitcnt vmcnt(0)" ::: "memory");
    __builtin_amdgcn_s_barrier();
    if (t < 15) STAGE((t + 1) & 1);

    const __bf16* Kl = (const __bf16*)(ring + (t & 1) * 18432);
    const __bf16* Vl = Kl + 4608;

    f32x16 sA0 = {0,0,0,0,0,0,0,0,0,0,0,0,0,0,0,0};
    f32x16 sA1 = {0,0,0,0,0,0,0,0,0,0,0,0,0,0,0,0};
    f32x16 sB0 = {0,0,0,0,0,0,0,0,0,0,0,0,0,0,0,0};
    f32x16 sB1 = {0,0,0,0,0,0,0,0,0,0,0,0,0,0,0,0};
    {
      bf16x8 kf[8];
#pragma unroll
      for (int dc = 0; dc < 4; ++dc)
        kf[dc] = *(const bf16x8*)(Kl + l31 * 72 + dc * 16 + hi * 8);
#pragma unroll
      for (int dc = 0; dc < 4; ++dc)
        kf[4 + dc] = *(const bf16x8*)(Kl + (32 + l31) * 72 + dc * 16 + hi * 8);
      __builtin_amdgcn_s_setprio(1);
#pragma unroll
      for (int dc = 0; dc < 4; ++dc) {
        sA0 = MFMA32(kf[dc], qfA[dc], sA0);
        sB0 = MFMA32(kf[dc], qfB[dc], sB0);
        sA1 = MFMA32(kf[4 + dc], qfA[dc], sA1);
        sB1 = MFMA32(kf[4 + dc], qfB[dc], sB1);
      }
      __builtin_amdgcn_s_setprio(0);
    }

    unsigned pwA[4][4], pwB[4][4];
    SMPACK(sA0, sA1, pwA, lnA);
    SMPACK(sB0, sB1, pwB, lnB);

    {
      bf16x8 vf[8];
#pragma unroll
      for (int c = 0; c < 4; ++c)
        vf[c] = *(const bf16x8*)(Vl + l31 * 72 + c * 16 + hi * 8);
#pragma unroll
      for (int c = 0; c < 4; ++c)
        vf[4 + c] = *(const bf16x8*)(Vl + (32 + l31) * 72 + c * 16 + hi * 8);
      __builtin_amdgcn_s_setprio(1);
#pragma unroll
      for (int c = 0; c < 4; ++c) {
        union { unsigned u[4]; bf16x8 v; } pa, pb;
        pa.u[0] = pwA[c][0]; pa.u[1] = pwA[c][1]; pa.u[2] = pwA[c][2]; pa.u[3] = pwA[c][3];
        pb.u[0] = pwB[c][0]; pb.u[1] = pwB[c][1]; pb.u[2] = pwB[c][2]; pb.u[3] = pwB[c][3];
        oA0 = MFMA32(pa.v, vf[c], oA0);
        oB0 = MFMA32(pb.v, vf[c], oB0);
        oA1 = MFMA32(pa.v, vf[4 + c], oA1);
        oB1 = MFMA32(pb.v, vf[4 + c], oB1);
      }
      __builtin_amdgcn_s_setprio(0);
    }
  }

  float lA = lnA + __shfl_xor(lnA, 32, 64);
  float lB = lnB + __shfl_xor(lnB, 32, 64);

  // ---- cross-group combine: O = O_g0 + O_g1, ln = ln_g0 + ln_g1 (no max merge needed) ----
  __syncthreads();   // all staging LDS reads done; safe to overlay
  f32x4* qbase = (f32x4*)(Lsm + wg * 16384);
  float* lnp = (float*)(Lsm + 65536) + (size_t)(wg * 64 + lane) * 2;
  if (g == 1) {
    // quad-interleaved store: quad i of this lane at [i*64 + lane] -> conflict-free
#pragma unroll
    for (int i = 0; i < 4; ++i) {
      f32x4 q0v = {oA0[i*4+0], oA0[i*4+1], oA0[i*4+2], oA0[i*4+3]};
      f32x4 q1v = {oA1[i*4+0], oA1[i*4+1], oA1[i*4+2], oA1[i*4+3]};
      f32x4 q2v = {oB0[i*4+0], oB0[i*4+1], oB0[i*4+2], oB0[i*4+3]};
      f32x4 q3v = {oB1[i*4+0], oB1[i*4+1], oB1[i*4+2], oB1[i*4+3]};
      qbase[(0 + i) * 64 + lane] = q0v;
      qbase[(4 + i) * 64 + lane] = q1v;
      qbase[(8 + i) * 64 + lane] = q2v;
      qbase[(12 + i) * 64 + lane] = q3v;
    }
    lnp[0] = lA; lnp[1] = lB;
  }
  __syncthreads();
  if (g == 0) {
#pragma unroll
    for (int i = 0; i < 4; ++i) {
      f32x4 q0v = qbase[(0 + i) * 64 + lane];
      f32x4 q1v = qbase[(4 + i) * 64 + lane];
      f32x4 q2v = qbase[(8 + i) * 64 + lane];
      f32x4 q3v = qbase[(12 + i) * 64 + lane];
#pragma unroll
      for (int r = 0; r < 4; ++r) {
        oA0[i*4+r] += q0v[r];
        oA1[i*4+r] += q1v[r];
        oB0[i*4+r] += q2v[r];
        oB1[i*4+r] += q3v[r];
      }
    }
    lA += lnp[0]; lB += lnp[1];
    float invA = 1.0f / lA, invB = 1.0f / lB;
    __bf16* Ob = AO + (size_t)(b * 2048 + q0) * 1024 + h * 64;
#pragma unroll
    for (int r = 0; r < 16; ++r) {
      int qr = (r & 3) + 8 * (r >> 2) + 4 * hi;
      float ivA = __shfl(invA, qr, 64);
      float ivB = __shfl(invB, qr, 64);
      Ob[(size_t)qr * 1024 + l31] = (__bf16)(oA0[r] * ivA);
      Ob[(size_t)qr * 1024 + 32 + l31] = (__bf16)(oA1[r] * ivA);
      Ob[(size_t)(32 + qr) * 1024 + l31] = (__bf16)(oB0[r] * ivB);
      Ob[(size_t)(32 + qr) * 1024 + 32 + l31] = (__bf16)(oB1[r] * ivB);
    }
  }
}

extern "C" void kernel_launch(void* const* d_in, const int* in_sizes, int n_in,
                              void* d_out, int out_size, void* d_ws, size_t ws_size,
                              hipStream_t stream) {
  const float* X    = (const float*)d_in[0];
  const float* Wqkv = (const float*)d_in[1];
  const float* Wout = (const float*)d_in[2];
  const float* bout = (const float*)d_in[3];
  float* out = (float*)d_out;
  char* ws = (char*)d_ws;

  __bf16* Xb  = (__bf16*)(ws);                 // 16,777,216 B
  __bf16* Wqt = (__bf16*)(ws + 16777216);      //  6,291,456 B  [3072][1024]
  __bf16* Wot = (__bf16*)(ws + 23068672);      //  2,097,152 B  [1024][1024]
  __bf16* QKb = (__bf16*)(ws + 25165824);      // 33,554,432 B  [8192][2048] (Q|K)
  __bf16* Vtb = (__bf16*)(ws + 58720256);      // 16,777,216 B  [4][1024][2048]
  __bf16* AOb = (__bf16*)(ws + 75497472);      // 16,777,216 B  [8192][1024]

  k_prep<<<3072, 256, 0, stream>>>(X, Wqkv, Wout, Xb, Wqt, Wot);
  k_gemm128<0><<<1536, 256, 0, stream>>>(Xb, Wqt, 24, QKb, Vtb, nullptr, nullptr);
  k_attn<<<512, 512, 0, stream>>>(QKb, Vtb, AOb);
  k_gemm128<1><<<512, 256, 0, stream>>>(AOb, Wot, 8, nullptr, nullptr, out, bout);
}

// Round 15
// 184.789 us; speedup vs baseline: 3.3409x; 3.3409x over previous
//
#include <hip/hip_runtime.h>
#include <hip/hip_bf16.h>
#include <stdint.h>

#define DIMD 1024
#define NB 4
#define NT 2048
#define NH 16
#define BT (NB*NT)      /* 8192 */
#define NQKV (3*DIMD)   /* 3072 */

typedef __attribute__((ext_vector_type(8))) __bf16 bf16x8;
typedef __attribute__((ext_vector_type(4))) __bf16 bf16x4;
typedef __attribute__((ext_vector_type(4))) float f32x4;
typedef __attribute__((ext_vector_type(16))) float f32x16;

#define MFMA16(a,b,c) __builtin_amdgcn_mfma_f32_16x16x32_bf16((a),(b),(c),0,0,0)
#define MFMA32(a,b,c) __builtin_amdgcn_mfma_f32_32x32x16_bf16((a),(b),(c),0,0,0)

// (1/sqrt(1024)) * log2(e) — folded into Q at projection time
#define QSCALE 0.0450842200277801f

__device__ __forceinline__ void gld16(const void* g, void* l) {
  __builtin_amdgcn_global_load_lds((const __attribute__((address_space(1))) void*)g,
                                   (__attribute__((address_space(3))) void*)l,
                                   16, 0, 0);
}

__device__ __forceinline__ unsigned pkbf(float a, float b) {
  unsigned short ua = __builtin_bit_cast(unsigned short, (__bf16)a);
  unsigned short ub = __builtin_bit_cast(unsigned short, (__bf16)b);
  return (unsigned)ua | ((unsigned)ub << 16);
}

// ---------------- fused prep: X f32->bf16  +  transpose-convert of both weights ----------
__global__ __launch_bounds__(256) void k_prep(const float* __restrict__ X,
                                              const float* __restrict__ Wqkv,
                                              const float* __restrict__ Wout,
                                              __bf16* __restrict__ Xb,
                                              __bf16* __restrict__ Wqt,
                                              __bf16* __restrict__ Wot) {
  __shared__ __bf16 t[64][72];
  const int bid = blockIdx.x, tid = threadIdx.x;
  if (bid < 1024) {
    const float* in; __bf16* out; int K, N, n0, k0;
    if (bid < 768) { in = Wqkv; out = Wqt; K = 1024; N = 3072; n0 = (bid % 48) * 64; k0 = (bid / 48) * 64; }
    else { int id = bid - 768; in = Wout; out = Wot; K = 1024; N = 1024; n0 = (id % 16) * 64; k0 = (id / 16) * 64; }
    int r = tid >> 2, c0 = (tid & 3) * 16;
    const float4* src = (const float4*)(in + (size_t)(k0 + r) * N + n0 + c0);
#pragma unroll
    for (int i = 0; i < 4; ++i) {
      float4 v = src[i];
      t[r][c0 + i*4 + 0] = (__bf16)v.x;
      t[r][c0 + i*4 + 1] = (__bf16)v.y;
      t[r][c0 + i*4 + 2] = (__bf16)v.z;
      t[r][c0 + i*4 + 3] = (__bf16)v.w;
    }
    __syncthreads();
    bf16x8 o0, o1;
#pragma unroll
    for (int i = 0; i < 8; ++i) o0[i] = t[c0 + i][r];
#pragma unroll
    for (int i = 0; i < 8; ++i) o1[i] = t[c0 + 8 + i][r];
    __bf16* dst = out + (size_t)(n0 + r) * K + k0 + c0;
    *(bf16x8*)dst = o0;
    *(bf16x8*)(dst + 8) = o1;
  } else {
    const int n4 = (BT * DIMD) / 4;
    int i = (bid - 1024) * 256 + tid;
    const int st = 2048 * 256;
    for (; i < n4; i += st) {
      float4 v = ((const float4*)X)[i];
      bf16x4 o;
      o[0] = (__bf16)v.x; o[1] = (__bf16)v.y; o[2] = (__bf16)v.z; o[3] = (__bf16)v.w;
      ((bf16x4*)Xb)[i] = o;
    }
  }
}

// ---------------- GEMM 128x128, ring-3 LDS, counted vmcnt, 3 blocks/CU ----------------
template<int MODE>
__global__ __launch_bounds__(256, 3) void k_gemm128(const __bf16* __restrict__ A,
                                                    const __bf16* __restrict__ Bt,
                                                    int nbx,
                                                    __bf16* __restrict__ oQK,
                                                    __bf16* __restrict__ oVt,
                                                    float* __restrict__ oF,
                                                    const float* __restrict__ bias) {
  constexpr int KK = 1024, KT = 32;
  __shared__ alignas(16) char L[3 * 16384];
  const int tid = threadIdx.x;
  const int lane = tid & 63, wid = tid >> 6;
  const int lr = lane & 15, lo = lane >> 4;
  const int wm = wid >> 1, wn = wid & 1;
  const int cpx = gridDim.x >> 3;   // grid % 8 == 0 for both launches
  const int swz = (blockIdx.x & 7) * cpx + (blockIdx.x >> 3);
  const int bx = swz % nbx, by = swz / nbx;
  const int m0 = by * 128, n0 = bx * 128;

  const char* gp[4];
  int loff[4];
#pragma unroll
  for (int j = 0; j < 4; ++j) {
    int c = j * 256 + tid;
    int isB = (c >= 512);
    int lc = c & 511;
    int row = lc >> 2, kof = (lc & 3) * 8;
    const __bf16* base = isB ? (Bt + (size_t)(n0 + row) * KK + kof)
                             : (A + (size_t)(m0 + row) * KK + kof);
    gp[j] = (const char*)base;
    loff[j] = c * 16;
  }
  auto STAGE = [&](int s) {
    char* bas = L + s * 16384;
    gld16(gp[0], bas + loff[0]); gp[0] += 64;
    gld16(gp[1], bas + loff[1]); gp[1] += 64;
    gld16(gp[2], bas + loff[2]); gp[2] += 64;
    gld16(gp[3], bas + loff[3]); gp[3] += 64;
  };

  f32x4 acc[4][4] = {};
  STAGE(0); STAGE(1);
  int xs = 2;

  for (int t = 0; t < KT; ++t) {
    if (t == KT - 1) asm volatile("s_waitcnt vmcnt(0)" ::: "memory");
    else             asm volatile("s_waitcnt vmcnt(4)" ::: "memory");
    asm volatile("s_barrier" ::: "memory");
    if (t <= KT - 3) { STAGE(xs); xs = (xs == 2) ? 0 : xs + 1; }
    const __bf16* fa = (const __bf16*)(L + (t % 3) * 16384) + (wm * 64 + lr) * 32 + lo * 8;
    const __bf16* fb = (const __bf16*)(L + (t % 3) * 16384 + 8192) + (wn * 64 + lr) * 32 + lo * 8;
    bf16x8 Af[4], Bf[4];
#pragma unroll
    for (int i = 0; i < 4; ++i) Af[i] = *(const bf16x8*)(fa + i * 512);
#pragma unroll
    for (int j = 0; j < 4; ++j) Bf[j] = *(const bf16x8*)(fb + j * 512);
    __builtin_amdgcn_s_setprio(1);
#pragma unroll
    for (int i = 0; i < 4; ++i)
#pragma unroll
      for (int j = 0; j < 4; ++j)
        acc[i][j] = MFMA16(Af[i], Bf[j], acc[i][j]);
    __builtin_amdgcn_s_setprio(0);
  }

  const int mb = m0 + wm * 64 + lo * 4;
  if (MODE == 0) {
    if (n0 < 1024) {        // Q: fold softmax scale in f32 (no extra rounding)
#pragma unroll
      for (int i = 0; i < 4; ++i)
#pragma unroll
        for (int j = 0; j < 4; ++j) {
          int col = n0 + wn * 64 + j * 16 + lr;
          int row = mb + i * 16;
#pragma unroll
          for (int r = 0; r < 4; ++r)
            oQK[(size_t)(row + r) * 2048 + col] = (__bf16)(acc[i][j][r] * QSCALE);
        }
    } else if (n0 < 2048) { // K
#pragma unroll
      for (int i = 0; i < 4; ++i)
#pragma unroll
        for (int j = 0; j < 4; ++j) {
          int col = n0 + wn * 64 + j * 16 + lr;
          int row = mb + i * 16;
#pragma unroll
          for (int r = 0; r < 4; ++r)
            oQK[(size_t)(row + r) * 2048 + col] = (__bf16)acc[i][j][r];
        }
    } else {                // V: write transposed Vt[b][d][t]
#pragma unroll
      for (int i = 0; i < 4; ++i)
#pragma unroll
        for (int j = 0; j < 4; ++j) {
          int dd = n0 - 2048 + wn * 64 + j * 16 + lr;
          int row = mb + i * 16;
          int bb = row >> 11, tt = row & 2047;
          bf16x4 pk;
#pragma unroll
          for (int r = 0; r < 4; ++r) pk[r] = (__bf16)acc[i][j][r];
          *(bf16x4*)(oVt + ((size_t)(bb << 10) + dd) * 2048 + tt) = pk;
        }
    }
  } else {
#pragma unroll
    for (int i = 0; i < 4; ++i)
#pragma unroll
      for (int j = 0; j < 4; ++j) {
        int col = n0 + wn * 64 + j * 16 + lr;
        float bv = bias[col];
        int row = mb + i * 16;
#pragma unroll
        for (int r = 0; r < 4; ++r)
          oF[(size_t)(row + r) * 1024 + col] = acc[i][j][r] + bv;
      }
  }
}

// ---------------- flash attention: ring-3 K/V LDS (pad-72), counted vmcnt — R9/R12 proven -
// 64 q/wave (two 32-q groups sharing K/V frags), swapped-QK^T 32x32, fixed-shift softmax.
__global__ __launch_bounds__(256, 2) void k_attn(const __bf16* __restrict__ QK,
                                                 const __bf16* __restrict__ Vt,
                                                 __bf16* __restrict__ AO) {
  __shared__ alignas(16) char Lsm[3 * 18432];
  const int tid = threadIdx.x, w = tid >> 6, lane = tid & 63;
  const int l31 = lane & 31, hi = lane >> 5;
  const int P = blockIdx.x;
  const int low3 = P & 7, g = P >> 3;
  const int qc = g & 7;
  const int bh = ((g >> 3) << 3) + low3;
  const int h = bh & 15, b = bh >> 4;
  const int q0 = qc * 256 + w * 64;

  bf16x8 qfA[4], qfB[4];
  {
    const __bf16* Qb = QK + (size_t)(b * 2048 + q0 + l31) * 2048 + h * 64 + hi * 8;
#pragma unroll
    for (int dc = 0; dc < 4; ++dc) qfA[dc] = *(const bf16x8*)(Qb + dc * 16);
    Qb += (size_t)32 * 2048;
#pragma unroll
    for (int dc = 0; dc < 4; ++dc) qfB[dc] = *(const bf16x8*)(Qb + dc * 16);
  }
  const __bf16* Kg = QK + (size_t)(b * 2048) * 2048 + 1024 + h * 64;
  const __bf16* Vg = Vt + (size_t)(b * 1024 + h * 64) * 2048;

  const bool nch5 = (tid < 128);
  const char* gp[5];
  int loff[5], advB[5];
#pragma unroll
  for (int j = 0; j < 5; ++j) {
    int c = (j < 4) ? (j * 256 + tid) : (1024 + tid);
    if (c > 1151) c = 1151;
    int isV = (c >= 576);
    int lc = isV ? c - 576 : c;
    int row = lc / 9, col = lc - row * 9; if (col == 8) col = 0;
    const __bf16* gsrc = isV ? (Vg + (size_t)row * 2048 + col * 8)
                             : (Kg + (size_t)row * 2048 + col * 8);
    gp[j] = (const char*)gsrc;
    loff[j] = c * 16;
    advB[j] = isV ? 128 : 262144;
  }

  f32x16 oA0 = {0,0,0,0,0,0,0,0,0,0,0,0,0,0,0,0};
  f32x16 oA1 = {0,0,0,0,0,0,0,0,0,0,0,0,0,0,0,0};
  f32x16 oB0 = {0,0,0,0,0,0,0,0,0,0,0,0,0,0,0,0};
  f32x16 oB1 = {0,0,0,0,0,0,0,0,0,0,0,0,0,0,0,0};
  float lnA = 0.f, lnB = 0.f;

  auto STAGE = [&](int s) {
    char* bas = Lsm + s * 18432;
    gld16(gp[0], bas + loff[0]); gp[0] += advB[0];
    gld16(gp[1], bas + loff[1]); gp[1] += advB[1];
    gld16(gp[2], bas + loff[2]); gp[2] += advB[2];
    gld16(gp[3], bas + loff[3]); gp[3] += advB[3];
    if (nch5) { gld16(gp[4], bas + loff[4]); gp[4] += advB[4]; }
  };

  auto SMPACK = [&](const f32x16& s0, const f32x16& s1, unsigned pw[4][4], float& ln) {
    float p0a[16], p1a[16];
#pragma unroll
    for (int r = 0; r < 16; ++r) {
      p0a[r] = __builtin_amdgcn_exp2f(s0[r]);
      p1a[r] = __builtin_amdgcn_exp2f(s1[r]);
    }
    float sA = 0.f, sB = 0.f, sC = 0.f, sD = 0.f;
#pragma unroll
    for (int r = 0; r < 4; ++r) {
      sA += p0a[r];      sB += p0a[4 + r];
      sC += p0a[8 + r];  sD += p0a[12 + r];
      sA += p1a[r];      sB += p1a[4 + r];
      sC += p1a[8 + r];  sD += p1a[12 + r];
    }
    ln += (sA + sB) + (sC + sD);
#pragma unroll
    for (int c = 0; c < 4; ++c) {
      const float* pp = (c < 2) ? p0a : p1a;
      const int rb = (c & 1) * 8;
      unsigned A01 = pkbf(pp[rb + 0], pp[rb + 1]);
      unsigned A23 = pkbf(pp[rb + 2], pp[rb + 3]);
      unsigned A45 = pkbf(pp[rb + 4], pp[rb + 5]);
      unsigned A67 = pkbf(pp[rb + 6], pp[rb + 7]);
      asm("v_permlane32_swap_b32 %0, %1" : "+v"(A01), "+v"(A45));
      asm("v_permlane32_swap_b32 %0, %1" : "+v"(A23), "+v"(A67));
      pw[c][0] = A01; pw[c][1] = A23; pw[c][2] = A45; pw[c][3] = A67;
    }
  };

  STAGE(0); STAGE(1);
  int xc = 0, xs = 2;

  for (int t = 0; t < 32; ++t) {
    if (t == 31)   asm volatile("s_waitcnt vmcnt(0)" ::: "memory");
    else if (nch5) asm volatile("s_waitcnt vmcnt(5)" ::: "memory");
    else           asm volatile("s_waitcnt vmcnt(4)" ::: "memory");
    __builtin_amdgcn_s_barrier();
    if (t <= 29) { STAGE(xs); xs = (xs == 2) ? 0 : xs + 1; }

    const __bf16* Kl = (const __bf16*)(Lsm + xc * 18432);
    const __bf16* Vl = Kl + 4608;

    f32x16 sA0 = {0,0,0,0,0,0,0,0,0,0,0,0,0,0,0,0};
    f32x16 sA1 = {0,0,0,0,0,0,0,0,0,0,0,0,0,0,0,0};
    f32x16 sB0 = {0,0,0,0,0,0,0,0,0,0,0,0,0,0,0,0};
    f32x16 sB1 = {0,0,0,0,0,0,0,0,0,0,0,0,0,0,0,0};
    {
      bf16x8 kf[8];
#pragma unroll
      for (int dc = 0; dc < 4; ++dc)
        kf[dc] = *(const bf16x8*)(Kl + l31 * 72 + dc * 16 + hi * 8);
#pragma unroll
      for (int dc = 0; dc < 4; ++dc)
        kf[4 + dc] = *(const bf16x8*)(Kl + (32 + l31) * 72 + dc * 16 + hi * 8);
      __builtin_amdgcn_s_setprio(1);
#pragma unroll
      for (int dc = 0; dc < 4; ++dc) {
        sA0 = MFMA32(kf[dc], qfA[dc], sA0);
        sB0 = MFMA32(kf[dc], qfB[dc], sB0);
        sA1 = MFMA32(kf[4 + dc], qfA[dc], sA1);
        sB1 = MFMA32(kf[4 + dc], qfB[dc], sB1);
      }
      __builtin_amdgcn_s_setprio(0);
    }

    unsigned pwA[4][4], pwB[4][4];
    SMPACK(sA0, sA1, pwA, lnA);
    SMPACK(sB0, sB1, pwB, lnB);

    {
      bf16x8 vf[8];
#pragma unroll
      for (int c = 0; c < 4; ++c)
        vf[c] = *(const bf16x8*)(Vl + l31 * 72 + c * 16 + hi * 8);
#pragma unroll
      for (int c = 0; c < 4; ++c)
        vf[4 + c] = *(const bf16x8*)(Vl + (32 + l31) * 72 + c * 16 + hi * 8);
      __builtin_amdgcn_s_setprio(1);
#pragma unroll
      for (int c = 0; c < 4; ++c) {
        union { unsigned u[4]; bf16x8 v; } pa, pb;
        pa.u[0] = pwA[c][0]; pa.u[1] = pwA[c][1]; pa.u[2] = pwA[c][2]; pa.u[3] = pwA[c][3];
        pb.u[0] = pwB[c][0]; pb.u[1] = pwB[c][1]; pb.u[2] = pwB[c][2]; pb.u[3] = pwB[c][3];
        oA0 = MFMA32(pa.v, vf[c], oA0);
        oB0 = MFMA32(pb.v, vf[c], oB0);
        oA1 = MFMA32(pa.v, vf[4 + c], oA1);
        oB1 = MFMA32(pb.v, vf[4 + c], oB1);
      }
      __builtin_amdgcn_s_setprio(0);
    }

    xc = (xc == 2) ? 0 : xc + 1;
  }

  float lA = lnA + __shfl_xor(lnA, 32, 64);
  float lB = lnB + __shfl_xor(lnB, 32, 64);
  float invA = 1.0f / lA, invB = 1.0f / lB;
  __bf16* Ob = AO + (size_t)(b * 2048 + q0) * 1024 + h * 64;
#pragma unroll
  for (int r = 0; r < 16; ++r) {
    int qr = (r & 3) + 8 * (r >> 2) + 4 * hi;
    float ivA = __shfl(invA, qr, 64);
    float ivB = __shfl(invB, qr, 64);
    Ob[(size_t)qr * 1024 + l31] = (__bf16)(oA0[r] * ivA);
    Ob[(size_t)qr * 1024 + 32 + l31] = (__bf16)(oA1[r] * ivA);
    Ob[(size_t)(32 + qr) * 1024 + l31] = (__bf16)(oB0[r] * ivB);
    Ob[(size_t)(32 + qr) * 1024 + 32 + l31] = (__bf16)(oB1[r] * ivB);
  }
}

extern "C" void kernel_launch(void* const* d_in, const int* in_sizes, int n_in,
                              void* d_out, int out_size, void* d_ws, size_t ws_size,
                              hipStream_t stream) {
  const float* X    = (const float*)d_in[0];
  const float* Wqkv = (const float*)d_in[1];
  const float* Wout = (const float*)d_in[2];
  const float* bout = (const float*)d_in[3];
  float* out = (float*)d_out;
  char* ws = (char*)d_ws;

  __bf16* Xb  = (__bf16*)(ws);                 // 16,777,216 B
  __bf16* Wqt = (__bf16*)(ws + 16777216);      //  6,291,456 B  [3072][1024]
  __bf16* Wot = (__bf16*)(ws + 23068672);      //  2,097,152 B  [1024][1024]
  __bf16* QKb = (__bf16*)(ws + 25165824);      // 33,554,432 B  [8192][2048] (Q|K)
  __bf16* Vtb = (__bf16*)(ws + 58720256);      // 16,777,216 B  [4][1024][2048]
  __bf16* AOb = (__bf16*)(ws + 75497472);      // 16,777,216 B  [8192][1024]

  k_prep<<<3072, 256, 0, stream>>>(X, Wqkv, Wout, Xb, Wqt, Wot);
  k_gemm128<0><<<1536, 256, 0, stream>>>(Xb, Wqt, 24, QKb, Vtb, nullptr, nullptr);
  k_attn<<<512, 256, 0, stream>>>(QKb, Vtb, AOb);
  k_gemm128<1><<<512, 256, 0, stream>>>(AOb, Wot, 8, nullptr, nullptr, out, bout);
}